// Round 6
// baseline (22267.201 us; speedup 1.0000x reference)
//
#include <hip/hip_runtime.h>
#include <hip/hip_bf16.h>

#define TT 512
#define BB 64
#define DD 512
#define HH 512
#define LL 2
#define GG 2048   // 4*H
#define NWG 64    // weight-slice WGs per layer
#define NWGT 128  // total WGs (both layers)
#define NTHR 256

typedef __attribute__((ext_vector_type(8))) short bf16x8;
typedef __attribute__((ext_vector_type(4))) float f32x4;

__device__ __forceinline__ ushort f2bf(float f) {
  unsigned u = __float_as_uint(f);
  unsigned r = (u + 0x7fffu + ((u >> 16) & 1u)) >> 16;
  return (ushort)r;
}
__device__ __forceinline__ float bf2f(ushort h) {
  return __uint_as_float(((unsigned)h) << 16);
}
__device__ __forceinline__ float sigmoidf(float x) { return 1.f / (1.f + expf(-x)); }

// ---- flag-array grid barrier over NWGT WGs: WG i release-stores flags[i];
// threads 0..NWGT-1 each poll one flag (relaxed agent-scope); trailing fence
// gives acquire ordering. No RMW serialization.
__device__ __forceinline__ void gbar2(int* flags, int wg, int phase) {
  __syncthreads();
  if (threadIdx.x < NWGT) {
    if (threadIdx.x == 0) {
      __threadfence();
      __hip_atomic_store(&flags[wg], phase, __ATOMIC_RELEASE, __HIP_MEMORY_SCOPE_AGENT);
    }
    while (__hip_atomic_load(&flags[threadIdx.x], __ATOMIC_RELAXED,
                             __HIP_MEMORY_SCOPE_AGENT) < phase) {
      __builtin_amdgcn_s_sleep(1);
    }
    __threadfence();
  }
  __syncthreads();
}

__device__ __forceinline__ void blockReduce4(float& a, float& b, float& c, float& d,
                                             volatile float* red) {
  #pragma unroll
  for (int off = 32; off > 0; off >>= 1) {
    a += __shfl_down(a, off);
    b += __shfl_down(b, off);
    c += __shfl_down(c, off);
    d += __shfl_down(d, off);
  }
  int lane = threadIdx.x & 63, wv = threadIdx.x >> 6;
  __syncthreads();
  if (lane == 0) { red[wv] = a; red[4 + wv] = b; red[8 + wv] = c; red[12 + wv] = d; }
  __syncthreads();
  a = red[0] + red[1] + red[2] + red[3];
  b = red[4] + red[5] + red[6] + red[7];
  c = red[8] + red[9] + red[10] + red[11];
  d = red[12] + red[13] + red[14] + red[15];
}

// f32 -> bf16 hi, row-major
__global__ void cvt_kernel(const float* __restrict__ src, ushort* __restrict__ dst, int n) {
  int i = (blockIdx.x * blockDim.x + threadIdx.x) * 4;
  int stride = gridDim.x * blockDim.x * 4;
  for (; i < n; i += stride) {
    float4 v = *(const float4*)(src + i);
    ushort4 o;
    o.x = f2bf(v.x); o.y = f2bf(v.y); o.z = f2bf(v.z); o.w = f2bf(v.w);
    *(ushort4*)(dst + i) = o;
  }
}

// W lo-part in MFMA-fragment order per weight-slice WG:
// blob[sl][((ks*2+nt)*64 + kq*16 + krow)*8 + j] = lo(W[grow][k0+j]),
// grow = ((lr>>3)<<9)+(sl<<3)+(lr&7), lr=nt*16+krow, k0=ks*32+kq*8.
__global__ void cvt_wlo_kernel(const float* __restrict__ W, ushort* __restrict__ blob) {
  int gid = blockIdx.x * blockDim.x + threadIdx.x;
  int sl = gid >> 11;
  int r  = gid & 2047;
  int ks = r >> 7;
  int nt = (r >> 6) & 1;
  int kq = (r >> 4) & 3;
  int krow = r & 15;
  int lr = nt * 16 + krow;
  int grow = ((lr >> 3) << 9) + (sl << 3) + (lr & 7);
  int k0 = ks * 32 + kq * 8;
  const float* src = W + grow * 512 + k0;
  ushort* dst = blob + (size_t)sl * 16384 + r * 8;
  #pragma unroll
  for (int j = 0; j < 8; ++j) {
    float v = src[j];
    ushort hi = f2bf(v);
    dst[j] = f2bf(v - bf2f(hi));
  }
}

// Single pipelined kernel: WGs 0..63 = layer 0, 64..127 = layer 1.
// Iteration it: layer l runs step t = it - l. ys ring of 2 slots carries
// layer-0 output to layer-1 (write ph2 of it, read ph1 of it+1, 1 barrier apart;
// overwrite of a slot is 2+ barriers after its last read).
__global__ __launch_bounds__(NTHR) void recur2_kernel(
    const float*  __restrict__ x32,
    ushort* __restrict__ ysHi, ushort* __restrict__ ysLo,   // [2][B][H] ring
    const ushort* __restrict__ WiB, const ushort* __restrict__ WhB,     // hi [L][G][512]
    const ushort* __restrict__ WiLoF, const ushort* __restrict__ WhLoF, // [L][64][16384]
    const float* __restrict__ bi, const float* __restrict__ bh,
    const float* __restrict__ a_i2h, const float* __restrict__ b_i2h,
    const float* __restrict__ a_h2h, const float* __restrict__ b_h2h,
    const float* __restrict__ a_cell, const float* __restrict__ b_cell,
    const float* __restrict__ h0, const float* __restrict__ c0,   // [L][B][H]
    ushort* __restrict__ hsthi, ushort* __restrict__ hstlo,       // [L][B][H]
    float*  __restrict__ cst,                                     // [L][B][H]
    float*  __restrict__ h2h_raw, float* __restrict__ i2h_raw,    // [L][B][G]
    float*  __restrict__ out_f,                                   // [T][B][H]
    int* __restrict__ flags)                                      // [128]
{
  const int wg  = blockIdx.x;   // 0..127
  const int lw  = wg >> 6;      // layer
  const int bg  = wg & 63;      // weight-slice id == phase-2 batch row
  const int tid = threadIdx.x;
  const int lane = tid & 63;
  const int wv   = tid >> 6;
  const int krow = lane & 15;
  const int kq   = lane >> 4;

  __shared__ ushort WhL[32 * 512];   // hi weights, XOR-swizzled rows
  __shared__ ushort WiL[32 * 512];
  __shared__ float biasH[32], biasI[32];
  __shared__ float red[16];

  const ushort* WiBl = WiB + (size_t)lw * GG * DD;
  const ushort* WhBl = WhB + (size_t)lw * GG * HH;
  const float* bil = bi + lw * GG;
  const float* bhl = bh + lw * GG;
  const float* ai2 = a_i2h + lw * GG;
  const float* bi2 = b_i2h + lw * GG;
  const float* ah2 = a_h2h + lw * GG;
  const float* bh2 = b_h2h + lw * GG;
  const float* acl = a_cell + lw * HH;
  const float* bcl = b_cell + lw * HH;

  for (int idx = tid; idx < 2048; idx += NTHR) {   // 16B chunks
    int lr = idx >> 6;
    int ck = idx & 63;
    int grow = ((lr >> 3) << 9) + (bg << 3) + (lr & 7);
    int boff = (lr << 10) + ((ck << 4) ^ ((lr & 7) << 4));
    *(uint4*)((char*)WhL + boff) = *(const uint4*)(WhBl + grow * 512 + ck * 8);
    *(uint4*)((char*)WiL + boff) = *(const uint4*)(WiBl + grow * 512 + ck * 8);
  }
  if (tid < 32) {
    int grow = ((tid >> 3) << 9) + (bg << 3) + (tid & 7);
    biasH[tid] = bhl[grow];
    biasI[tid] = bil[grow];
  }
  for (int j = tid; j < HH; j += NTHR) {   // init own batch row (lw, bg)
    float hv = h0[(size_t)(lw * BB + bg) * HH + j];
    ushort hh = f2bf(hv);
    hsthi[(size_t)(lw * BB + bg) * HH + j] = hh;
    hstlo[(size_t)(lw * BB + bg) * HH + j] = f2bf(hv - bf2f(hh));
    cst[(size_t)(lw * BB + bg) * HH + j] = c0[(size_t)(lw * BB + bg) * HH + j];
  }
  int phase = 1;
  gbar2(flags, wg, phase++);

  const ushort* wloH = WhLoF + ((size_t)lw * NWG + bg) * 16384;
  const ushort* wloI = WiLoF + ((size_t)lw * NWG + bg) * 16384;
  const int arow = wv * 16 + krow;
  const ushort* hHrow = hsthi + ((size_t)lw * BB + arow) * HH;
  const ushort* hLrow = hstlo + ((size_t)lw * BB + arow) * HH;
  float* h2hW = h2h_raw + (size_t)lw * BB * GG;
  float* i2hW = i2h_raw + (size_t)lw * BB * GG;

  for (int it = 0; it <= TT; ++it) {
    const int t = it - lw;
    const bool active = (t >= 0) && (t < TT);   // block-uniform

    if (active) {
      // ===== phase 1: split-bf16 h2h + i2h GEMM slices (3-term ~fp32) =====
      f32x4 aH[2] = {{0.f,0.f,0.f,0.f},{0.f,0.f,0.f,0.f}};
      f32x4 aI[2] = {{0.f,0.f,0.f,0.f},{0.f,0.f,0.f,0.f}};
      const int slot = t & 1;
      #pragma unroll 4
      for (int ks = 0; ks < 16; ++ks) {
        int k0 = ks * 32 + kq * 8;
        bf16x8 ahh = *(const bf16x8*)(hHrow + k0);
        bf16x8 ahl = *(const bf16x8*)(hLrow + k0);
        bf16x8 axh, axl;
        if (lw == 0) {
          const float* xp = x32 + (size_t)t * (BB * DD) + arow * DD + k0;
          #pragma unroll
          for (int j = 0; j < 8; ++j) {
            float v = xp[j];
            ushort hi = f2bf(v);
            axh[j] = (short)hi;
            axl[j] = (short)f2bf(v - bf2f(hi));
          }
        } else {
          size_t o = (size_t)slot * (BB * HH) + arow * HH + k0;
          axh = *(const bf16x8*)(ysHi + o);
          axl = *(const bf16x8*)(ysLo + o);
        }
        #pragma unroll
        for (int nt = 0; nt < 2; ++nt) {
          int lr = nt * 16 + krow;
          int boff = (lr << 10) + ((k0 * 2) ^ ((lr & 7) << 4));
          bf16x8 whh = *(const bf16x8*)((const char*)WhL + boff);
          bf16x8 wih = *(const bf16x8*)((const char*)WiL + boff);
          int foff = ((ks * 2 + nt) * 64 + kq * 16 + krow) * 8;
          bf16x8 whl = *(const bf16x8*)(wloH + foff);
          bf16x8 wil = *(const bf16x8*)(wloI + foff);
          aH[nt] = __builtin_amdgcn_mfma_f32_16x16x32_bf16(ahh, whh, aH[nt], 0, 0, 0);
          aH[nt] = __builtin_amdgcn_mfma_f32_16x16x32_bf16(ahl, whh, aH[nt], 0, 0, 0);
          aH[nt] = __builtin_amdgcn_mfma_f32_16x16x32_bf16(ahh, whl, aH[nt], 0, 0, 0);
          aI[nt] = __builtin_amdgcn_mfma_f32_16x16x32_bf16(axh, wih, aI[nt], 0, 0, 0);
          aI[nt] = __builtin_amdgcn_mfma_f32_16x16x32_bf16(axl, wih, aI[nt], 0, 0, 0);
          aI[nt] = __builtin_amdgcn_mfma_f32_16x16x32_bf16(axh, wil, aI[nt], 0, 0, 0);
        }
      }
      #pragma unroll
      for (int nt = 0; nt < 2; ++nt) {
        int lr = nt * 16 + krow;
        int grow = ((lr >> 3) << 9) + (bg << 3) + (lr & 7);
        float bH = biasH[lr], bI = biasI[lr];
        #pragma unroll
        for (int r = 0; r < 4; ++r) {
          int b = wv * 16 + kq * 4 + r;   // D-row = batch
          h2hW[b * GG + grow] = aH[nt][r] + bH;
          i2hW[b * GG + grow] = aI[nt][r] + bI;
        }
      }
    }
    gbar2(flags, wg, phase++);

    if (active) {
      // ===== phase 2: LNs + gates + cell, batch row = bg =====
      const int b = bg;
      const int j0 = tid * 2;
      const float* hrow = h2hW + b * GG;
      const float* irow = i2hW + b * GG;
      float2 hr[4], ir[4];
      float sh = 0.f, qh = 0.f, si = 0.f, qi = 0.f;
      #pragma unroll
      for (int g = 0; g < 4; ++g) {
        hr[g] = *(const float2*)(hrow + g * HH + j0);
        ir[g] = *(const float2*)(irow + g * HH + j0);
        sh += hr[g].x + hr[g].y; qh += hr[g].x * hr[g].x + hr[g].y * hr[g].y;
        si += ir[g].x + ir[g].y; qi += ir[g].x * ir[g].x + ir[g].y * ir[g].y;
      }
      blockReduce4(sh, qh, si, qi, red);
      float mh = sh * (1.f / GG), mi = si * (1.f / GG);
      float vh = (qh - (float)GG * mh * mh) * (1.f / (GG - 1));
      float vi = (qi - (float)GG * mi * mi) * (1.f / (GG - 1));
      float rh = 1.f / sqrtf(vh + 1e-6f);
      float ri = 1.f / sqrtf(vi + 1e-6f);
      float pre[4][2];
      #pragma unroll
      for (int g = 0; g < 4; ++g) {
        int idx = g * HH + j0;
        float2 aiv = *(const float2*)(ai2 + idx);
        float2 biv = *(const float2*)(bi2 + idx);
        float2 ahv = *(const float2*)(ah2 + idx);
        float2 bhv = *(const float2*)(bh2 + idx);
        pre[g][0] = aiv.x * (ir[g].x - mi) * ri + biv.x + ahv.x * (hr[g].x - mh) * rh + bhv.x;
        pre[g][1] = aiv.y * (ir[g].y - mi) * ri + biv.y + ahv.y * (hr[g].y - mh) * rh + bhv.y;
      }
      float i_0 = sigmoidf(pre[0][0]), i_1 = sigmoidf(pre[0][1]);
      float f_0 = sigmoidf(pre[1][0]), f_1 = sigmoidf(pre[1][1]);
      float o_0 = sigmoidf(pre[2][0]), o_1 = sigmoidf(pre[2][1]);
      float g_0 = tanhf(pre[3][0]),    g_1 = tanhf(pre[3][1]);
      float2 cv = *(const float2*)(cst + (size_t)(lw * BB + b) * HH + j0);
      float cr0 = cv.x * f_0 + i_0 * g_0;
      float cr1 = cv.y * f_1 + i_1 * g_1;
      float sc = cr0 + cr1, qc = cr0 * cr0 + cr1 * cr1, d1 = 0.f, d2 = 0.f;
      blockReduce4(sc, qc, d1, d2, red);
      float mc = sc * (1.f / HH);
      float vc = (qc - (float)HH * mc * mc) * (1.f / (HH - 1));
      float rc = 1.f / sqrtf(vc + 1e-6f);
      float2 acv = *(const float2*)(acl + j0);
      float2 bcv = *(const float2*)(bcl + j0);
      float cn0 = acv.x * (cr0 - mc) * rc + bcv.x;
      float cn1 = acv.y * (cr1 - mc) * rc + bcv.y;
      *(float2*)(cst + (size_t)(lw * BB + b) * HH + j0) = make_float2(cn0, cn1);
      float hn0 = o_0 * tanhf(cn0);
      float hn1 = o_1 * tanhf(cn1);
      ushort hh0 = f2bf(hn0), hh1 = f2bf(hn1);
      ushort hl0 = f2bf(hn0 - bf2f(hh0)), hl1 = f2bf(hn1 - bf2f(hh1));
      size_t hsto = (size_t)(lw * BB + b) * HH + j0;
      hsthi[hsto] = hh0;  hsthi[hsto + 1] = hh1;
      hstlo[hsto] = hl0;  hstlo[hsto + 1] = hl1;
      if (lw == 0) {
        size_t o = (size_t)(t & 1) * (BB * HH) + b * HH + j0;
        ysHi[o] = hh0; ysHi[o + 1] = hh1;
        ysLo[o] = hl0; ysLo[o + 1] = hl1;
      } else {
        *(float2*)(out_f + (size_t)t * (BB * HH) + b * HH + j0) = make_float2(hn0, hn1);
      }
    }
    gbar2(flags, wg, phase++);
  }
}

extern "C" void kernel_launch(void* const* d_in, const int* in_sizes, int n_in,
                              void* d_out, int out_size, void* d_ws, size_t ws_size,
                              hipStream_t stream) {
  const float* x      = (const float*)d_in[0];
  const float* h0     = (const float*)d_in[1];
  const float* c0     = (const float*)d_in[2];
  const float* Wi     = (const float*)d_in[3];
  const float* bi     = (const float*)d_in[4];
  const float* Wh     = (const float*)d_in[5];
  const float* bh     = (const float*)d_in[6];
  const float* a_i2h  = (const float*)d_in[7];
  const float* b_i2h  = (const float*)d_in[8];
  const float* a_h2h  = (const float*)d_in[9];
  const float* b_h2h  = (const float*)d_in[10];
  const float* a_cell = (const float*)d_in[11];
  const float* b_cell = (const float*)d_in[12];
  float* out = (float*)d_out;

  char* p = (char*)d_ws;
  size_t off = 0;
  auto alloc = [&](size_t bytes) -> char* {
    char* r = p + off;
    off = (off + bytes + 255) & ~(size_t)255;
    return r;
  };
  int*    flags  = (int*)   alloc(NWGT * 4);
  ushort* WiBf   = (ushort*)alloc((size_t)LL * GG * DD * 2);        // hi
  ushort* WhBf   = (ushort*)alloc((size_t)LL * GG * HH * 2);        // hi
  ushort* WiLoF  = (ushort*)alloc((size_t)LL * NWG * 16384 * 2);    // lo frag blobs
  ushort* WhLoF  = (ushort*)alloc((size_t)LL * NWG * 16384 * 2);
  ushort* ysHi   = (ushort*)alloc((size_t)2 * BB * HH * 2);         // 2-slot ring
  ushort* ysLo   = (ushort*)alloc((size_t)2 * BB * HH * 2);
  float*  h2h_r  = (float*) alloc((size_t)LL * BB * GG * 4);
  float*  i2h_r  = (float*) alloc((size_t)LL * BB * GG * 4);
  ushort* hstHi  = (ushort*)alloc((size_t)LL * BB * HH * 2);
  ushort* hstLo  = (ushort*)alloc((size_t)LL * BB * HH * 2);
  float*  cst    = (float*) alloc((size_t)LL * BB * HH * 4);

  hipMemsetAsync(flags, 0, NWGT * 4, stream);
  hipLaunchKernelGGL(cvt_kernel, dim3(512), dim3(256), 0, stream, Wi, WiBf, LL * GG * DD);
  hipLaunchKernelGGL(cvt_kernel, dim3(512), dim3(256), 0, stream, Wh, WhBf, LL * GG * HH);
  for (int l = 0; l < LL; ++l) {
    hipLaunchKernelGGL(cvt_wlo_kernel, dim3(512), dim3(256), 0, stream,
                       Wi + (size_t)l * GG * DD, WiLoF + (size_t)l * NWG * 16384);
    hipLaunchKernelGGL(cvt_wlo_kernel, dim3(512), dim3(256), 0, stream,
                       Wh + (size_t)l * GG * HH, WhLoF + (size_t)l * NWG * 16384);
  }

  hipLaunchKernelGGL(recur2_kernel, dim3(NWGT), dim3(NTHR), 0, stream,
      x, ysHi, ysLo,
      WiBf, WhBf, WiLoF, WhLoF,
      bi, bh, a_i2h, b_i2h, a_h2h, b_h2h, a_cell, b_cell,
      h0, c0,
      hstHi, hstLo, cst, h2h_r, i2h_r,
      out, flags);
}

// Round 7
// 17632.272 us; speedup vs baseline: 1.2629x; 1.2629x over previous
//
#include <hip/hip_runtime.h>
#include <hip/hip_bf16.h>

#define TT 512
#define BB 64
#define DD 512
#define HH 512
#define LL 2
#define GG 2048   // 4*H
#define NWG 64    // weight-slice WGs per layer
#define NWGT 128  // total WGs (both layers)
#define NTHR 256

typedef __attribute__((ext_vector_type(8))) short bf16x8;
typedef __attribute__((ext_vector_type(4))) float f32x4;

__device__ __forceinline__ ushort f2bf(float f) {
  unsigned u = __float_as_uint(f);
  unsigned r = (u + 0x7fffu + ((u >> 16) & 1u)) >> 16;
  return (ushort)r;
}
__device__ __forceinline__ float bf2f(ushort h) {
  return __uint_as_float(((unsigned)h) << 16);
}
__device__ __forceinline__ float sigmoidf(float x) { return 1.f / (1.f + expf(-x)); }

// ---- coherent (agent-scope, L2-bypass) access helpers for cross-WG data ----
__device__ __forceinline__ void st_f32c(float* p, float v) {
  __hip_atomic_store(p, v, __ATOMIC_RELAXED, __HIP_MEMORY_SCOPE_AGENT);
}
__device__ __forceinline__ void st_u32c(uint* p, uint v) {
  __hip_atomic_store(p, v, __ATOMIC_RELAXED, __HIP_MEMORY_SCOPE_AGENT);
}
__device__ __forceinline__ unsigned long long ld_u64c(const void* p) {
  return __hip_atomic_load((const unsigned long long*)p, __ATOMIC_RELAXED,
                           __HIP_MEMORY_SCOPE_AGENT);
}
__device__ __forceinline__ float2 ld_f32x2c(const float* p) {
  union { unsigned long long u; float2 f; } c;
  c.u = ld_u64c(p);
  return c.f;
}
__device__ __forceinline__ bf16x8 ld_bf8c(const ushort* p) {   // 16B, 16B-aligned
  union { unsigned long long u[2]; bf16x8 v; } c;
  c.u[0] = ld_u64c(p);
  c.u[1] = ld_u64c(p + 4);
  return c.v;
}

// ---- flag-array grid barrier, NO cache-wide fences ----
// Data written before the barrier uses sc1 (agent-atomic) stores; __syncthreads
// drains vmcnt so those stores are at the coherence point before the RELEASE
// flag store. Readers use sc1 loads, so no acquire-invalidate is needed.
__device__ __forceinline__ void gbar2(int* flags, int wg, int phase) {
  __syncthreads();
  if (threadIdx.x < NWGT) {
    if (threadIdx.x == 0) {
      __hip_atomic_store(&flags[wg], phase, __ATOMIC_RELEASE, __HIP_MEMORY_SCOPE_AGENT);
    }
    while (__hip_atomic_load(&flags[threadIdx.x], __ATOMIC_RELAXED,
                             __HIP_MEMORY_SCOPE_AGENT) < phase) {
      __builtin_amdgcn_s_sleep(1);
    }
  }
  __syncthreads();
}

__device__ __forceinline__ void blockReduce4(float& a, float& b, float& c, float& d,
                                             volatile float* red) {
  #pragma unroll
  for (int off = 32; off > 0; off >>= 1) {
    a += __shfl_down(a, off);
    b += __shfl_down(b, off);
    c += __shfl_down(c, off);
    d += __shfl_down(d, off);
  }
  int lane = threadIdx.x & 63, wv = threadIdx.x >> 6;
  __syncthreads();
  if (lane == 0) { red[wv] = a; red[4 + wv] = b; red[8 + wv] = c; red[12 + wv] = d; }
  __syncthreads();
  a = red[0] + red[1] + red[2] + red[3];
  b = red[4] + red[5] + red[6] + red[7];
  c = red[8] + red[9] + red[10] + red[11];
  d = red[12] + red[13] + red[14] + red[15];
}

// f32 -> bf16 hi, row-major
__global__ void cvt_kernel(const float* __restrict__ src, ushort* __restrict__ dst, int n) {
  int i = (blockIdx.x * blockDim.x + threadIdx.x) * 4;
  int stride = gridDim.x * blockDim.x * 4;
  for (; i < n; i += stride) {
    float4 v = *(const float4*)(src + i);
    ushort4 o;
    o.x = f2bf(v.x); o.y = f2bf(v.y); o.z = f2bf(v.z); o.w = f2bf(v.w);
    *(ushort4*)(dst + i) = o;
  }
}

// Slice sl owns 32 CONTIGUOUS weight rows: grow = (sl>>4)*512 + (sl&15)*32 + lr,
// lr in [0,32). Lo-part blob in MFMA-fragment order:
// blob[sl][((ks*2+nt)*64 + kq*16 + krow)*8 + j] = lo(W[grow(sl,nt*16+krow)][ks*32+kq*8+j])
__global__ void cvt_wlo_kernel(const float* __restrict__ W, ushort* __restrict__ blob) {
  int gid = blockIdx.x * blockDim.x + threadIdx.x;
  int sl = gid >> 11;
  int r  = gid & 2047;
  int ks = r >> 7;
  int nt = (r >> 6) & 1;
  int kq = (r >> 4) & 3;
  int krow = r & 15;
  int lr = nt * 16 + krow;
  int grow = ((sl >> 4) << 9) + ((sl & 15) << 5) + lr;
  int k0 = ks * 32 + kq * 8;
  const float* src = W + grow * 512 + k0;
  ushort* dst = blob + (size_t)sl * 16384 + r * 8;
  #pragma unroll
  for (int j = 0; j < 8; ++j) {
    float v = src[j];
    ushort hi = f2bf(v);
    dst[j] = f2bf(v - bf2f(hi));
  }
}

// Pipelined 2-layer LN-LSTM. WGs 0..63 = layer 0, 64..127 = layer 1.
// Iteration it: layer l runs step t = it - l. All cross-WG arrays accessed
// through sc1 agent atomics; weights/x/blobs stay L2-cached (never invalidated).
__global__ __launch_bounds__(NTHR) void recur2_kernel(
    const float*  __restrict__ x32,
    ushort* __restrict__ ysHi, ushort* __restrict__ ysLo,   // [2][B][H] ring
    const ushort* __restrict__ WiB, const ushort* __restrict__ WhB,     // hi [L][G][512]
    const ushort* __restrict__ WiLoF, const ushort* __restrict__ WhLoF, // [L][64][16384]
    const float* __restrict__ bi, const float* __restrict__ bh,
    const float* __restrict__ a_i2h, const float* __restrict__ b_i2h,
    const float* __restrict__ a_h2h, const float* __restrict__ b_h2h,
    const float* __restrict__ a_cell, const float* __restrict__ b_cell,
    const float* __restrict__ h0, const float* __restrict__ c0,   // [L][B][H]
    ushort* __restrict__ hsthi, ushort* __restrict__ hstlo,       // [L][B][H]
    float*  __restrict__ h2h_raw, float* __restrict__ i2h_raw,    // [L][B][G]
    float*  __restrict__ out_f,                                   // [T][B][H]
    int* __restrict__ flags)                                      // [128]
{
  const int wg  = blockIdx.x;   // 0..127
  const int lw  = wg >> 6;      // layer
  const int bg  = wg & 63;      // weight-slice id == phase-2 batch row
  const int tid = threadIdx.x;
  const int lane = tid & 63;
  const int wv   = tid >> 6;
  const int krow = lane & 15;
  const int kq   = lane >> 4;
  const int gbase = ((bg >> 4) << 9) + ((bg & 15) << 5);   // slice's first col

  __shared__ ushort WhL[32 * 512];   // hi weights, XOR-swizzled rows
  __shared__ ushort WiL[32 * 512];
  __shared__ float biasH[32], biasI[32];
  __shared__ float red[16];

  const ushort* WiBl = WiB + (size_t)lw * GG * DD;
  const ushort* WhBl = WhB + (size_t)lw * GG * HH;
  const float* bil = bi + lw * GG;
  const float* bhl = bh + lw * GG;
  const float* ai2 = a_i2h + lw * GG;
  const float* bi2 = b_i2h + lw * GG;
  const float* ah2 = a_h2h + lw * GG;
  const float* bh2 = b_h2h + lw * GG;
  const float* acl = a_cell + lw * HH;
  const float* bcl = b_cell + lw * HH;

  for (int idx = tid; idx < 2048; idx += NTHR) {   // 16B chunks, rows contiguous
    int lr = idx >> 6;
    int ck = idx & 63;
    int boff = (lr << 10) + ((ck << 4) ^ ((lr & 7) << 4));
    *(uint4*)((char*)WhL + boff) = *(const uint4*)(WhBl + (gbase + lr) * 512 + ck * 8);
    *(uint4*)((char*)WiL + boff) = *(const uint4*)(WiBl + (gbase + lr) * 512 + ck * 8);
  }
  if (tid < 32) {
    biasH[tid] = bhl[gbase + tid];
    biasI[tid] = bil[gbase + tid];
  }
  // cell state lives in registers of its owner WG (row bg of layer lw)
  const int j0 = tid * 2;
  float creg0 = c0[(size_t)(lw * BB + bg) * HH + j0];
  float creg1 = c0[(size_t)(lw * BB + bg) * HH + j0 + 1];
  {  // init h state (coherent stores: read by all WGs of this layer next phase)
    float hv0 = h0[(size_t)(lw * BB + bg) * HH + j0];
    float hv1 = h0[(size_t)(lw * BB + bg) * HH + j0 + 1];
    ushort hh0 = f2bf(hv0), hh1 = f2bf(hv1);
    ushort hl0 = f2bf(hv0 - bf2f(hh0)), hl1 = f2bf(hv1 - bf2f(hh1));
    size_t o = (size_t)(lw * BB + bg) * HH + j0;
    st_u32c((uint*)&hsthi[o], (uint)hh0 | ((uint)hh1 << 16));
    st_u32c((uint*)&hstlo[o], (uint)hl0 | ((uint)hl1 << 16));
  }
  int phase = 1;
  gbar2(flags, wg, phase++);

  const ushort* wloH = WhLoF + ((size_t)lw * NWG + bg) * 16384;
  const ushort* wloI = WiLoF + ((size_t)lw * NWG + bg) * 16384;
  const int arow = wv * 16 + krow;
  const ushort* hHrow = hsthi + ((size_t)lw * BB + arow) * HH;
  const ushort* hLrow = hstlo + ((size_t)lw * BB + arow) * HH;
  float* h2hW = h2h_raw + (size_t)lw * BB * GG;
  float* i2hW = i2h_raw + (size_t)lw * BB * GG;

  for (int it = 0; it <= TT; ++it) {
    const int t = it - lw;
    const bool active = (t >= 0) && (t < TT);   // block-uniform

    if (active) {
      // ===== phase 1: split-bf16 h2h + i2h GEMM slices (3-term ~fp32) =====
      f32x4 aH[2] = {{0.f,0.f,0.f,0.f},{0.f,0.f,0.f,0.f}};
      f32x4 aI[2] = {{0.f,0.f,0.f,0.f},{0.f,0.f,0.f,0.f}};
      const int slot = t & 1;
      #pragma unroll 4
      for (int ks = 0; ks < 16; ++ks) {
        int k0 = ks * 32 + kq * 8;
        bf16x8 ahh = ld_bf8c(hHrow + k0);
        bf16x8 ahl = ld_bf8c(hLrow + k0);
        bf16x8 axh, axl;
        if (lw == 0) {
          const float* xp = x32 + (size_t)t * (BB * DD) + arow * DD + k0;  // cached
          #pragma unroll
          for (int j = 0; j < 8; ++j) {
            float v = xp[j];
            ushort hi = f2bf(v);
            axh[j] = (short)hi;
            axl[j] = (short)f2bf(v - bf2f(hi));
          }
        } else {
          size_t o = (size_t)slot * (BB * HH) + arow * HH + k0;
          axh = ld_bf8c(ysHi + o);
          axl = ld_bf8c(ysLo + o);
        }
        #pragma unroll
        for (int nt = 0; nt < 2; ++nt) {
          int lr = nt * 16 + krow;
          int boff = (lr << 10) + ((k0 * 2) ^ ((lr & 7) << 4));
          bf16x8 whh = *(const bf16x8*)((const char*)WhL + boff);
          bf16x8 wih = *(const bf16x8*)((const char*)WiL + boff);
          int foff = ((ks * 2 + nt) * 64 + kq * 16 + krow) * 8;
          bf16x8 whl = *(const bf16x8*)(wloH + foff);   // L2-cached
          bf16x8 wil = *(const bf16x8*)(wloI + foff);
          aH[nt] = __builtin_amdgcn_mfma_f32_16x16x32_bf16(ahh, whh, aH[nt], 0, 0, 0);
          aH[nt] = __builtin_amdgcn_mfma_f32_16x16x32_bf16(ahl, whh, aH[nt], 0, 0, 0);
          aH[nt] = __builtin_amdgcn_mfma_f32_16x16x32_bf16(ahh, whl, aH[nt], 0, 0, 0);
          aI[nt] = __builtin_amdgcn_mfma_f32_16x16x32_bf16(axh, wih, aI[nt], 0, 0, 0);
          aI[nt] = __builtin_amdgcn_mfma_f32_16x16x32_bf16(axl, wih, aI[nt], 0, 0, 0);
          aI[nt] = __builtin_amdgcn_mfma_f32_16x16x32_bf16(axh, wil, aI[nt], 0, 0, 0);
        }
      }
      // epilogue: bias add + coherent stores (contiguous cols -> dense lines)
      #pragma unroll
      for (int nt = 0; nt < 2; ++nt) {
        int lr = nt * 16 + krow;
        int col = gbase + lr;
        float bH = biasH[lr], bI = biasI[lr];
        #pragma unroll
        for (int r = 0; r < 4; ++r) {
          int b = wv * 16 + kq * 4 + r;   // batch row
          st_f32c(&h2hW[b * GG + col], aH[nt][r] + bH);
          st_f32c(&i2hW[b * GG + col], aI[nt][r] + bI);
        }
      }
    }
    gbar2(flags, wg, phase++);

    if (active) {
      // ===== phase 2: LNs + gates + cell, batch row = bg =====
      const float* hrow = h2hW + bg * GG;
      const float* irow = i2hW + bg * GG;
      float2 hr[4], ir[4];
      float sh = 0.f, qh = 0.f, si = 0.f, qi = 0.f;
      #pragma unroll
      for (int g = 0; g < 4; ++g) {
        hr[g] = ld_f32x2c(hrow + g * HH + j0);
        ir[g] = ld_f32x2c(irow + g * HH + j0);
        sh += hr[g].x + hr[g].y; qh += hr[g].x * hr[g].x + hr[g].y * hr[g].y;
        si += ir[g].x + ir[g].y; qi += ir[g].x * ir[g].x + ir[g].y * ir[g].y;
      }
      blockReduce4(sh, qh, si, qi, red);
      float mh = sh * (1.f / GG), mi = si * (1.f / GG);
      float vh = (qh - (float)GG * mh * mh) * (1.f / (GG - 1));
      float vi = (qi - (float)GG * mi * mi) * (1.f / (GG - 1));
      float rh = 1.f / sqrtf(vh + 1e-6f);
      float ri = 1.f / sqrtf(vi + 1e-6f);
      float pre[4][2];
      #pragma unroll
      for (int g = 0; g < 4; ++g) {
        int idx = g * HH + j0;
        float2 aiv = *(const float2*)(ai2 + idx);
        float2 biv = *(const float2*)(bi2 + idx);
        float2 ahv = *(const float2*)(ah2 + idx);
        float2 bhv = *(const float2*)(bh2 + idx);
        pre[g][0] = aiv.x * (ir[g].x - mi) * ri + biv.x + ahv.x * (hr[g].x - mh) * rh + bhv.x;
        pre[g][1] = aiv.y * (ir[g].y - mi) * ri + biv.y + ahv.y * (hr[g].y - mh) * rh + bhv.y;
      }
      float i_0 = sigmoidf(pre[0][0]), i_1 = sigmoidf(pre[0][1]);
      float f_0 = sigmoidf(pre[1][0]), f_1 = sigmoidf(pre[1][1]);
      float o_0 = sigmoidf(pre[2][0]), o_1 = sigmoidf(pre[2][1]);
      float g_0 = tanhf(pre[3][0]),    g_1 = tanhf(pre[3][1]);
      float cr0 = creg0 * f_0 + i_0 * g_0;
      float cr1 = creg1 * f_1 + i_1 * g_1;
      float sc = cr0 + cr1, qc = cr0 * cr0 + cr1 * cr1, d1 = 0.f, d2 = 0.f;
      blockReduce4(sc, qc, d1, d2, red);
      float mc = sc * (1.f / HH);
      float vc = (qc - (float)HH * mc * mc) * (1.f / (HH - 1));
      float rc = 1.f / sqrtf(vc + 1e-6f);
      float2 acv = *(const float2*)(acl + j0);
      float2 bcv = *(const float2*)(bcl + j0);
      creg0 = acv.x * (cr0 - mc) * rc + bcv.x;   // c_new stays in registers
      creg1 = acv.y * (cr1 - mc) * rc + bcv.y;
      float hn0 = o_0 * tanhf(creg0);
      float hn1 = o_1 * tanhf(creg1);
      ushort hh0 = f2bf(hn0), hh1 = f2bf(hn1);
      ushort hl0 = f2bf(hn0 - bf2f(hh0)), hl1 = f2bf(hn1 - bf2f(hh1));
      size_t hsto = (size_t)(lw * BB + bg) * HH + j0;
      st_u32c((uint*)&hsthi[hsto], (uint)hh0 | ((uint)hh1 << 16));
      st_u32c((uint*)&hstlo[hsto], (uint)hl0 | ((uint)hl1 << 16));
      if (lw == 0) {
        size_t o = (size_t)(t & 1) * (BB * HH) + bg * HH + j0;
        st_u32c((uint*)&ysHi[o], (uint)hh0 | ((uint)hh1 << 16));
        st_u32c((uint*)&ysLo[o], (uint)hl0 | ((uint)hl1 << 16));
      } else {
        *(float2*)(out_f + (size_t)t * (BB * HH) + bg * HH + j0) = make_float2(hn0, hn1);
      }
    }
    gbar2(flags, wg, phase++);
  }
}

extern "C" void kernel_launch(void* const* d_in, const int* in_sizes, int n_in,
                              void* d_out, int out_size, void* d_ws, size_t ws_size,
                              hipStream_t stream) {
  const float* x      = (const float*)d_in[0];
  const float* h0     = (const float*)d_in[1];
  const float* c0     = (const float*)d_in[2];
  const float* Wi     = (const float*)d_in[3];
  const float* bi     = (const float*)d_in[4];
  const float* Wh     = (const float*)d_in[5];
  const float* bh     = (const float*)d_in[6];
  const float* a_i2h  = (const float*)d_in[7];
  const float* b_i2h  = (const float*)d_in[8];
  const float* a_h2h  = (const float*)d_in[9];
  const float* b_h2h  = (const float*)d_in[10];
  const float* a_cell = (const float*)d_in[11];
  const float* b_cell = (const float*)d_in[12];
  float* out = (float*)d_out;

  char* p = (char*)d_ws;
  size_t off = 0;
  auto alloc = [&](size_t bytes) -> char* {
    char* r = p + off;
    off = (off + bytes + 255) & ~(size_t)255;
    return r;
  };
  int*    flags  = (int*)   alloc(NWGT * 4);
  ushort* WiBf   = (ushort*)alloc((size_t)LL * GG * DD * 2);        // hi
  ushort* WhBf   = (ushort*)alloc((size_t)LL * GG * HH * 2);        // hi
  ushort* WiLoF  = (ushort*)alloc((size_t)LL * NWG * 16384 * 2);    // lo frag blobs
  ushort* WhLoF  = (ushort*)alloc((size_t)LL * NWG * 16384 * 2);
  ushort* ysHi   = (ushort*)alloc((size_t)2 * BB * HH * 2);         // 2-slot ring
  ushort* ysLo   = (ushort*)alloc((size_t)2 * BB * HH * 2);
  float*  h2h_r  = (float*) alloc((size_t)LL * BB * GG * 4);
  float*  i2h_r  = (float*) alloc((size_t)LL * BB * GG * 4);
  ushort* hstHi  = (ushort*)alloc((size_t)LL * BB * HH * 2);
  ushort* hstLo  = (ushort*)alloc((size_t)LL * BB * HH * 2);

  hipMemsetAsync(flags, 0, NWGT * 4, stream);
  hipLaunchKernelGGL(cvt_kernel, dim3(512), dim3(256), 0, stream, Wi, WiBf, LL * GG * DD);
  hipLaunchKernelGGL(cvt_kernel, dim3(512), dim3(256), 0, stream, Wh, WhBf, LL * GG * HH);
  for (int l = 0; l < LL; ++l) {
    hipLaunchKernelGGL(cvt_wlo_kernel, dim3(512), dim3(256), 0, stream,
                       Wi + (size_t)l * GG * DD, WiLoF + (size_t)l * NWG * 16384);
    hipLaunchKernelGGL(cvt_wlo_kernel, dim3(512), dim3(256), 0, stream,
                       Wh + (size_t)l * GG * HH, WhLoF + (size_t)l * NWG * 16384);
  }

  hipLaunchKernelGGL(recur2_kernel, dim3(NWGT), dim3(NTHR), 0, stream,
      x, ysHi, ysLo,
      WiBf, WhBf, WiLoF, WhLoF,
      bi, bh, a_i2h, b_i2h, a_h2h, b_h2h, a_cell, b_cell,
      h0, c0,
      hstHi, hstLo, h2h_r, i2h_r,
      out, flags);
}

// Round 9
// 14289.680 us; speedup vs baseline: 1.5583x; 1.2339x over previous
//
#include <hip/hip_runtime.h>
#include <hip/hip_bf16.h>

#define TT 512
#define BB 64
#define DD 512
#define HH 512
#define LL 2
#define GG 2048   // 4*H
#define NWG 64    // weight-slice WGs per layer
#define NWGT 128  // total WGs (both layers)
#define NTHR 256

typedef __attribute__((ext_vector_type(8))) short bf16x8;
typedef __attribute__((ext_vector_type(4))) float f32x4;

__device__ __forceinline__ ushort f2bf(float f) {
  unsigned u = __float_as_uint(f);
  unsigned r = (u + 0x7fffu + ((u >> 16) & 1u)) >> 16;
  return (ushort)r;
}
__device__ __forceinline__ float bf2f(ushort h) {
  return __uint_as_float(((unsigned)h) << 16);
}
__device__ __forceinline__ float sigmoidf(float x) { return 1.f / (1.f + expf(-x)); }

// ---- coherent (agent-scope) access helpers for cross-WG data ----
__device__ __forceinline__ void st_f32c(float* p, float v) {
  __hip_atomic_store(p, v, __ATOMIC_RELAXED, __HIP_MEMORY_SCOPE_AGENT);
}
__device__ __forceinline__ void st_u32c(uint* p, uint v) {
  __hip_atomic_store(p, v, __ATOMIC_RELAXED, __HIP_MEMORY_SCOPE_AGENT);
}
__device__ __forceinline__ unsigned long long ld_u64c(const void* p) {
  return __hip_atomic_load((const unsigned long long*)p, __ATOMIC_RELAXED,
                           __HIP_MEMORY_SCOPE_AGENT);
}
__device__ __forceinline__ float2 ld_f32x2c(const float* p) {
  union { unsigned long long u; float2 f; } c;
  c.u = ld_u64c(p);
  return c.f;
}
__device__ __forceinline__ bf16x8 ld_bf8c(const ushort* p) {   // 16B, 16B-aligned
  union { unsigned long long u[2]; bf16x8 v; } c;
  c.u[0] = ld_u64c(p);
  c.u[1] = ld_u64c(p + 4);
  return c.v;
}

// ---- epoch-based grid barrier (low poll pressure) ----
// 1) every WG's thread 0 release-stores flags[wg] = phase (parallel arrivals)
// 2) ONLY WG 0 aggregates: threads 0..NWGT-1 poll flags[tid]
// 3) WG 0 thread 0 release-stores epoch = phase (single line)
// 4) every other WG: only thread 0 polls epoch, then __syncthreads
// Concurrent UC pollers: ~2*NWGT instead of NWGT*NWGT.
__device__ __forceinline__ void gbar3(int* flags, int* epoch, int wg, int phase) {
  __syncthreads();   // drains vmcnt: prior sc1 stores are at coherence point
  if (threadIdx.x == 0) {
    __hip_atomic_store(&flags[wg], phase, __ATOMIC_RELEASE, __HIP_MEMORY_SCOPE_AGENT);
  }
  if (wg == 0) {
    if (threadIdx.x < NWGT) {
      while (__hip_atomic_load(&flags[threadIdx.x], __ATOMIC_RELAXED,
                               __HIP_MEMORY_SCOPE_AGENT) < phase) {
        __builtin_amdgcn_s_sleep(2);
      }
    }
    __syncthreads();
    if (threadIdx.x == 0) {
      __hip_atomic_store(epoch, phase, __ATOMIC_RELEASE, __HIP_MEMORY_SCOPE_AGENT);
    }
  }
  if (threadIdx.x == 0) {
    while (__hip_atomic_load(epoch, __ATOMIC_RELAXED,
                             __HIP_MEMORY_SCOPE_AGENT) < phase) {
      __builtin_amdgcn_s_sleep(4);
    }
  }
  __syncthreads();
}

__device__ __forceinline__ void blockReduce4(float& a, float& b, float& c, float& d,
                                             volatile float* red) {
  #pragma unroll
  for (int off = 32; off > 0; off >>= 1) {
    a += __shfl_down(a, off);
    b += __shfl_down(b, off);
    c += __shfl_down(c, off);
    d += __shfl_down(d, off);
  }
  int lane = threadIdx.x & 63, wv = threadIdx.x >> 6;
  __syncthreads();
  if (lane == 0) { red[wv] = a; red[4 + wv] = b; red[8 + wv] = c; red[12 + wv] = d; }
  __syncthreads();
  a = red[0] + red[1] + red[2] + red[3];
  b = red[4] + red[5] + red[6] + red[7];
  c = red[8] + red[9] + red[10] + red[11];
  d = red[12] + red[13] + red[14] + red[15];
}

// f32 -> bf16 hi, row-major
__global__ void cvt_kernel(const float* __restrict__ src, ushort* __restrict__ dst, int n) {
  int i = (blockIdx.x * blockDim.x + threadIdx.x) * 4;
  int stride = gridDim.x * blockDim.x * 4;
  for (; i < n; i += stride) {
    float4 v = *(const float4*)(src + i);
    ushort4 o;
    o.x = f2bf(v.x); o.y = f2bf(v.y); o.z = f2bf(v.z); o.w = f2bf(v.w);
    *(ushort4*)(dst + i) = o;
  }
}

// Slice sl owns 32 CONTIGUOUS weight rows: grow = (sl>>4)*512 + (sl&15)*32 + lr.
// Lo-part blob in MFMA-fragment order:
// blob[sl][((ks*2+nt)*64 + kq*16 + krow)*8 + j] = lo(W[grow(sl,nt*16+krow)][ks*32+kq*8+j])
__global__ void cvt_wlo_kernel(const float* __restrict__ W, ushort* __restrict__ blob) {
  int gid = blockIdx.x * blockDim.x + threadIdx.x;
  int sl = gid >> 11;
  int r  = gid & 2047;
  int ks = r >> 7;
  int nt = (r >> 6) & 1;
  int kq = (r >> 4) & 3;
  int krow = r & 15;
  int lr = nt * 16 + krow;
  int grow = ((sl >> 4) << 9) + ((sl & 15) << 5) + lr;
  int k0 = ks * 32 + kq * 8;
  const float* src = W + grow * 512 + k0;
  ushort* dst = blob + (size_t)sl * 16384 + r * 8;
  #pragma unroll
  for (int j = 0; j < 8; ++j) {
    float v = src[j];
    ushort hi = f2bf(v);
    dst[j] = f2bf(v - bf2f(hi));
  }
}

// Pipelined 2-layer LN-LSTM. WGs 0..63 = layer 0, 64..127 = layer 1.
// Iteration it: layer l runs step t = it - l.
__global__ __launch_bounds__(NTHR) void recur2_kernel(
    const float*  __restrict__ x32,
    ushort* __restrict__ ysHi, ushort* __restrict__ ysLo,   // [2][B][H] ring
    const ushort* __restrict__ WiB, const ushort* __restrict__ WhB,     // hi [L][G][512]
    const ushort* __restrict__ WiLoF, const ushort* __restrict__ WhLoF, // [L][64][16384]
    const float* __restrict__ bi, const float* __restrict__ bh,
    const float* __restrict__ a_i2h, const float* __restrict__ b_i2h,
    const float* __restrict__ a_h2h, const float* __restrict__ b_h2h,
    const float* __restrict__ a_cell, const float* __restrict__ b_cell,
    const float* __restrict__ h0, const float* __restrict__ c0,   // [L][B][H]
    ushort* __restrict__ hsthi, ushort* __restrict__ hstlo,       // [L][B][H]
    float*  __restrict__ h2h_raw, float* __restrict__ i2h_raw,    // [L][B][G]
    float*  __restrict__ out_f,                                   // [T][B][H]
    int* __restrict__ flags, int* __restrict__ epoch)
{
  const int wg  = blockIdx.x;   // 0..127
  const int lw  = wg >> 6;      // layer
  const int bg  = wg & 63;      // weight-slice id == phase-2 batch row
  const int tid = threadIdx.x;
  const int lane = tid & 63;
  const int wv   = tid >> 6;
  const int krow = lane & 15;
  const int kq   = lane >> 4;
  const int gbase = ((bg >> 4) << 9) + ((bg & 15) << 5);   // slice's first col

  __shared__ ushort WhL[32 * 512];   // hi weights, XOR-swizzled rows
  __shared__ ushort WiL[32 * 512];
  __shared__ float biasH[32], biasI[32];
  __shared__ float red[16];

  const ushort* WiBl = WiB + (size_t)lw * GG * DD;
  const ushort* WhBl = WhB + (size_t)lw * GG * HH;
  const float* bil = bi + lw * GG;
  const float* bhl = bh + lw * GG;
  const float* ai2 = a_i2h + lw * GG;
  const float* bi2 = b_i2h + lw * GG;
  const float* ah2 = a_h2h + lw * GG;
  const float* bh2 = b_h2h + lw * GG;
  const float* acl = a_cell + lw * HH;
  const float* bcl = b_cell + lw * HH;

  for (int idx = tid; idx < 2048; idx += NTHR) {   // 16B chunks, rows contiguous
    int lr = idx >> 6;
    int ck = idx & 63;
    int boff = (lr << 10) + ((ck << 4) ^ ((lr & 7) << 4));
    *(uint4*)((char*)WhL + boff) = *(const uint4*)(WhBl + (gbase + lr) * 512 + ck * 8);
    *(uint4*)((char*)WiL + boff) = *(const uint4*)(WiBl + (gbase + lr) * 512 + ck * 8);
  }
  if (tid < 32) {
    biasH[tid] = bhl[gbase + tid];
    biasI[tid] = bil[gbase + tid];
  }
  // cell state lives in registers of its owner WG (row bg of layer lw)
  const int j0 = tid * 2;
  float creg0 = c0[(size_t)(lw * BB + bg) * HH + j0];
  float creg1 = c0[(size_t)(lw * BB + bg) * HH + j0 + 1];
  {  // init h state (coherent stores)
    float hv0 = h0[(size_t)(lw * BB + bg) * HH + j0];
    float hv1 = h0[(size_t)(lw * BB + bg) * HH + j0 + 1];
    ushort hh0 = f2bf(hv0), hh1 = f2bf(hv1);
    ushort hl0 = f2bf(hv0 - bf2f(hh0)), hl1 = f2bf(hv1 - bf2f(hh1));
    size_t o = (size_t)(lw * BB + bg) * HH + j0;
    st_u32c((uint*)&hsthi[o], (uint)hh0 | ((uint)hh1 << 16));
    st_u32c((uint*)&hstlo[o], (uint)hl0 | ((uint)hl1 << 16));
  }
  int phase = 1;
  gbar3(flags, epoch, wg, phase++);

  const ushort* wloH = WhLoF + ((size_t)lw * NWG + bg) * 16384;
  const ushort* wloI = WiLoF + ((size_t)lw * NWG + bg) * 16384;
  const int arow = wv * 16 + krow;
  const ushort* hHrow = hsthi + ((size_t)lw * BB + arow) * HH;
  const ushort* hLrow = hstlo + ((size_t)lw * BB + arow) * HH;
  float* h2hW = h2h_raw + (size_t)lw * BB * GG;
  float* i2hW = i2h_raw + (size_t)lw * BB * GG;

  for (int it = 0; it <= TT; ++it) {
    const int t = it - lw;
    const bool active = (t >= 0) && (t < TT);   // block-uniform

    if (active) {
      // ===== phase 1: split-bf16 h2h + i2h GEMM slices (3-term ~fp32) =====
      f32x4 aH[2] = {{0.f,0.f,0.f,0.f},{0.f,0.f,0.f,0.f}};
      f32x4 aI[2] = {{0.f,0.f,0.f,0.f},{0.f,0.f,0.f,0.f}};
      const int slot = t & 1;
      #pragma unroll 4
      for (int ks = 0; ks < 16; ++ks) {
        int k0 = ks * 32 + kq * 8;
        bf16x8 ahh = ld_bf8c(hHrow + k0);
        bf16x8 ahl = ld_bf8c(hLrow + k0);
        bf16x8 axh, axl;
        if (lw == 0) {
          const float* xp = x32 + (size_t)t * (BB * DD) + arow * DD + k0;  // cached
          #pragma unroll
          for (int j = 0; j < 8; ++j) {
            float v = xp[j];
            ushort hi = f2bf(v);
            axh[j] = (short)hi;
            axl[j] = (short)f2bf(v - bf2f(hi));
          }
        } else {
          size_t o = (size_t)slot * (BB * HH) + arow * HH + k0;
          axh = ld_bf8c(ysHi + o);
          axl = ld_bf8c(ysLo + o);
        }
        #pragma unroll
        for (int nt = 0; nt < 2; ++nt) {
          int lr = nt * 16 + krow;
          int boff = (lr << 10) + ((k0 * 2) ^ ((lr & 7) << 4));
          bf16x8 whh = *(const bf16x8*)((const char*)WhL + boff);
          bf16x8 wih = *(const bf16x8*)((const char*)WiL + boff);
          int foff = ((ks * 2 + nt) * 64 + kq * 16 + krow) * 8;
          bf16x8 whl = *(const bf16x8*)(wloH + foff);   // L2-cached
          bf16x8 wil = *(const bf16x8*)(wloI + foff);
          aH[nt] = __builtin_amdgcn_mfma_f32_16x16x32_bf16(ahh, whh, aH[nt], 0, 0, 0);
          aH[nt] = __builtin_amdgcn_mfma_f32_16x16x32_bf16(ahl, whh, aH[nt], 0, 0, 0);
          aH[nt] = __builtin_amdgcn_mfma_f32_16x16x32_bf16(ahh, whl, aH[nt], 0, 0, 0);
          aI[nt] = __builtin_amdgcn_mfma_f32_16x16x32_bf16(axh, wih, aI[nt], 0, 0, 0);
          aI[nt] = __builtin_amdgcn_mfma_f32_16x16x32_bf16(axl, wih, aI[nt], 0, 0, 0);
          aI[nt] = __builtin_amdgcn_mfma_f32_16x16x32_bf16(axh, wil, aI[nt], 0, 0, 0);
        }
      }
      // epilogue: bias add + coherent stores (contiguous cols -> dense lines)
      #pragma unroll
      for (int nt = 0; nt < 2; ++nt) {
        int lr = nt * 16 + krow;
        int col = gbase + lr;
        float bH = biasH[lr], bI = biasI[lr];
        #pragma unroll
        for (int r = 0; r < 4; ++r) {
          int b = wv * 16 + kq * 4 + r;   // batch row
          st_f32c(&h2hW[b * GG + col], aH[nt][r] + bH);
          st_f32c(&i2hW[b * GG + col], aI[nt][r] + bI);
        }
      }
    }
    gbar3(flags, epoch, wg, phase++);

    if (active) {
      // ===== phase 2: LNs + gates + cell, batch row = bg =====
      const float* hrow = h2hW + bg * GG;
      const float* irow = i2hW + bg * GG;
      float2 hr[4], ir[4];
      float sh = 0.f, qh = 0.f, si = 0.f, qi = 0.f;
      #pragma unroll
      for (int g = 0; g < 4; ++g) {
        hr[g] = ld_f32x2c(hrow + g * HH + j0);
        ir[g] = ld_f32x2c(irow + g * HH + j0);
        sh += hr[g].x + hr[g].y; qh += hr[g].x * hr[g].x + hr[g].y * hr[g].y;
        si += ir[g].x + ir[g].y; qi += ir[g].x * ir[g].x + ir[g].y * ir[g].y;
      }
      blockReduce4(sh, qh, si, qi, red);
      float mh = sh * (1.f / GG), mi = si * (1.f / GG);
      float vh = (qh - (float)GG * mh * mh) * (1.f / (GG - 1));
      float vi = (qi - (float)GG * mi * mi) * (1.f / (GG - 1));
      float rh = 1.f / sqrtf(vh + 1e-6f);
      float ri = 1.f / sqrtf(vi + 1e-6f);
      float pre[4][2];
      #pragma unroll
      for (int g = 0; g < 4; ++g) {
        int idx = g * HH + j0;
        float2 aiv = *(const float2*)(ai2 + idx);
        float2 biv = *(const float2*)(bi2 + idx);
        float2 ahv = *(const float2*)(ah2 + idx);
        float2 bhv = *(const float2*)(bh2 + idx);
        pre[g][0] = aiv.x * (ir[g].x - mi) * ri + biv.x + ahv.x * (hr[g].x - mh) * rh + bhv.x;
        pre[g][1] = aiv.y * (ir[g].y - mi) * ri + biv.y + ahv.y * (hr[g].y - mh) * rh + bhv.y;
      }
      float i_0 = sigmoidf(pre[0][0]), i_1 = sigmoidf(pre[0][1]);
      float f_0 = sigmoidf(pre[1][0]), f_1 = sigmoidf(pre[1][1]);
      float o_0 = sigmoidf(pre[2][0]), o_1 = sigmoidf(pre[2][1]);
      float g_0 = tanhf(pre[3][0]),    g_1 = tanhf(pre[3][1]);
      float cr0 = creg0 * f_0 + i_0 * g_0;
      float cr1 = creg1 * f_1 + i_1 * g_1;
      float sc = cr0 + cr1, qc = cr0 * cr0 + cr1 * cr1, d1 = 0.f, d2 = 0.f;
      blockReduce4(sc, qc, d1, d2, red);
      float mc = sc * (1.f / HH);
      float vc = (qc - (float)HH * mc * mc) * (1.f / (HH - 1));
      float rc = 1.f / sqrtf(vc + 1e-6f);
      float2 acv = *(const float2*)(acl + j0);
      float2 bcv = *(const float2*)(bcl + j0);
      creg0 = acv.x * (cr0 - mc) * rc + bcv.x;   // c_new stays in registers
      creg1 = acv.y * (cr1 - mc) * rc + bcv.y;
      float hn0 = o_0 * tanhf(creg0);
      float hn1 = o_1 * tanhf(creg1);
      ushort hh0 = f2bf(hn0), hh1 = f2bf(hn1);
      ushort hl0 = f2bf(hn0 - bf2f(hh0)), hl1 = f2bf(hn1 - bf2f(hh1));
      size_t hsto = (size_t)(lw * BB + bg) * HH + j0;
      st_u32c((uint*)&hsthi[hsto], (uint)hh0 | ((uint)hh1 << 16));
      st_u32c((uint*)&hstlo[hsto], (uint)hl0 | ((uint)hl1 << 16));
      if (lw == 0) {
        size_t o = (size_t)(t & 1) * (BB * HH) + bg * HH + j0;
        st_u32c((uint*)&ysHi[o], (uint)hh0 | ((uint)hh1 << 16));
        st_u32c((uint*)&ysLo[o], (uint)hl0 | ((uint)hl1 << 16));
      } else {
        *(float2*)(out_f + (size_t)t * (BB * HH) + bg * HH + j0) = make_float2(hn0, hn1);
      }
    }
    gbar3(flags, epoch, wg, phase++);
  }
}

extern "C" void kernel_launch(void* const* d_in, const int* in_sizes, int n_in,
                              void* d_out, int out_size, void* d_ws, size_t ws_size,
                              hipStream_t stream) {
  const float* x      = (const float*)d_in[0];
  const float* h0     = (const float*)d_in[1];
  const float* c0     = (const float*)d_in[2];
  const float* Wi     = (const float*)d_in[3];
  const float* bi     = (const float*)d_in[4];
  const float* Wh     = (const float*)d_in[5];
  const float* bh     = (const float*)d_in[6];
  const float* a_i2h  = (const float*)d_in[7];
  const float* b_i2h  = (const float*)d_in[8];
  const float* a_h2h  = (const float*)d_in[9];
  const float* b_h2h  = (const float*)d_in[10];
  const float* a_cell = (const float*)d_in[11];
  const float* b_cell = (const float*)d_in[12];
  float* out = (float*)d_out;

  char* p = (char*)d_ws;
  size_t off = 0;
  auto alloc = [&](size_t bytes) -> char* {
    char* r = p + off;
    off = (off + bytes + 255) & ~(size_t)255;
    return r;
  };
  int*    flags  = (int*)   alloc(1024);          // [0..127] arrivals
  int*    epoch  = (int*)   alloc(256);           // own line
  ushort* WiBf   = (ushort*)alloc((size_t)LL * GG * DD * 2);        // hi
  ushort* WhBf   = (ushort*)alloc((size_t)LL * GG * HH * 2);        // hi
  ushort* WiLoF  = (ushort*)alloc((size_t)LL * NWG * 16384 * 2);    // lo frag blobs
  ushort* WhLoF  = (ushort*)alloc((size_t)LL * NWG * 16384 * 2);
  ushort* ysHi   = (ushort*)alloc((size_t)2 * BB * HH * 2);         // 2-slot ring
  ushort* ysLo   = (ushort*)alloc((size_t)2 * BB * HH * 2);
  float*  h2h_r  = (float*) alloc((size_t)LL * BB * GG * 4);
  float*  i2h_r  = (float*) alloc((size_t)LL * BB * GG * 4);
  ushort* hstHi  = (ushort*)alloc((size_t)LL * BB * HH * 2);
  ushort* hstLo  = (ushort*)alloc((size_t)LL * BB * HH * 2);

  hipMemsetAsync(flags, 0, 1024, stream);
  hipMemsetAsync(epoch, 0, 256, stream);
  hipLaunchKernelGGL(cvt_kernel, dim3(512), dim3(256), 0, stream, Wi, WiBf, LL * GG * DD);
  hipLaunchKernelGGL(cvt_kernel, dim3(512), dim3(256), 0, stream, Wh, WhBf, LL * GG * HH);
  for (int l = 0; l < LL; ++l) {
    hipLaunchKernelGGL(cvt_wlo_kernel, dim3(512), dim3(256), 0, stream,
                       Wi + (size_t)l * GG * DD, WiLoF + (size_t)l * NWG * 16384);
    hipLaunchKernelGGL(cvt_wlo_kernel, dim3(512), dim3(256), 0, stream,
                       Wh + (size_t)l * GG * HH, WhLoF + (size_t)l * NWG * 16384);
  }

  hipLaunchKernelGGL(recur2_kernel, dim3(NWGT), dim3(NTHR), 0, stream,
      x, ysHi, ysLo,
      WiBf, WhBf, WiLoF, WhLoF,
      bi, bh, a_i2h, b_i2h, a_h2h, b_h2h, a_cell, b_cell,
      h0, c0,
      hstHi, hstLo, h2h_r, i2h_r,
      out, flags, epoch);
}